// Round 10
// baseline (91.189 us; speedup 1.0000x reference)
//
#include <hip/hip_runtime.h>
#include <hip/hip_bf16.h>

#define N_NODES 50000
#define N_EDGES 640000

typedef __attribute__((ext_vector_type(8))) short bf16x8;
typedef __attribute__((ext_vector_type(4))) float f32x4;

static __device__ __forceinline__ short f2bf(float f) {
    __hip_bfloat16 h = __float2bfloat16(f);
    return *reinterpret_cast<const short*>(&h);
}

static __device__ __forceinline__ float sgpr_f(const float* p) {
    return __uint_as_float(__builtin_amdgcn_readfirstlane(__float_as_uint(*p)));
}

__global__ __launch_bounds__(256)
void edge_hyper_kernel(const float* __restrict__ x,
                       const int* __restrict__ ei,      // int32 [2][E]
                       const float* __restrict__ ev,
                       const float* __restrict__ nrm,
                       const float* __restrict__ W1,
                       const float* __restrict__ b1,
                       const float* __restrict__ W2,
                       const float* __restrict__ b2,
                       float* __restrict__ out,
                       int ngroups)
{
    // B tiles in LDS: [c][o][k] bf16, k-row padded 32->34 (2-way aliasing free).
    __shared__ short w2s[17 * 16 * 34];

    const int tid  = threadIdx.x;
    const int l    = tid & 63;
    const int r    = l & 15;         // A-row edge-in-group / D col o
    const int half = l >> 4;         // 0..3 -> k-range half*8..half*8+7

    // ---- cooperative W2/b2 -> bf16 LDS (c=16 is the b2 bias tile) ----
    for (int idx = tid; idx < 17 * 512; idx += 256) {
        const int c   = idx >> 9;
        const int rem = idx & 511;
        const int o   = rem >> 5;
        const int k   = rem & 31;
        const float v = (c < 16) ? W2[c * 512 + o * 32 + k] : b2[o * 32 + k];
        w2s[(c * 16 + o) * 34 + k] = f2bf(v);
    }

    // ---- W1/b1 pinned to SGPRs ----
    float w1c0[16], w1c1[16], w1c2[16], b1s[16];
    #pragma unroll
    for (int c = 0; c < 16; ++c) {
        w1c0[c] = sgpr_f(W1 + c);
        w1c1[c] = sgpr_f(W1 + 16 + c);
        w1c2[c] = sgpr_f(W1 + 32 + c);
        b1s[c]  = sgpr_f(b1 + c);
    }

    __syncthreads();   // w2s ready; no further sync

    // per-lane LDS base: tile c element (c*16+r)*34 + half*8  ->  wbase + c*544
    const short* wbase = &w2s[r * 34 + half * 8];

    const int wv = tid >> 6;
    const int nw = gridDim.x * 4;            // 8192 waves
    const int gw = blockIdx.x * 4 + wv;
    if (gw >= ngroups) return;
    const int eisel = (half >= 2 ? N_EDGES : 0);

    // pair (gA, gB=gA+nw) per iteration, stride 2*nw. Coverage over
    // gw in [0,nw): {gw, gw+nw, gw+2nw, ...} clipped to ngroups — exact.
    int gA = gw;
    int gB = gw + nw;

    // clamp helper target: the wave's own first group (always valid)
    #define CLAMPG(G) ((G) < ngroups ? (G) : gw)

    // ---- prologue: current pair idx + x gathers; next pair idx ----
    int idxA = ei[eisel + gA * 16 + r];
    int idxB = ei[eisel + CLAMPG(gB) * 16 + r];
    float4 xaA, xbA, xaB, xbB;
    {
        const float4* p = reinterpret_cast<const float4*>(
            x + (size_t)idxA * 16 + (half & 1) * 8);
        xaA = p[0]; xbA = p[1];
        const float4* q = reinterpret_cast<const float4*>(
            x + (size_t)idxB * 16 + (half & 1) * 8);
        xaB = q[0]; xbB = q[1];
    }
    int idxA1 = ei[eisel + CLAMPG(gA + 2 * nw) * 16 + r];
    int idxB1 = ei[eisel + CLAMPG(gB + 2 * nw) * 16 + r];

    while (gA < ngroups) {
        const bool vB = (gB < ngroups);
        const int gAs = gA;
        const int gBs = CLAMPG(gB);

        // ---- (1) idx loads for pair+2 ----
        const int idxA2 = ei[eisel + CLAMPG(gA + 4 * nw) * 16 + r];
        const int idxB2 = ei[eisel + CLAMPG(gB + 4 * nw) * 16 + r];

        // ---- (2) x-gathers for pair+1 from RESIDENT idx (no mid-iter dep) ----
        const float4* xp1 = reinterpret_cast<const float4*>(
            x + (size_t)idxA1 * 16 + (half & 1) * 8);
        const float4 xaA1 = xp1[0];
        const float4 xbA1 = xp1[1];
        const float4* xq1 = reinterpret_cast<const float4*>(
            x + (size_t)idxB1 * 16 + (half & 1) * 8);
        const float4 xaB1 = xq1[0];
        const float4 xbB1 = xq1[1];

        // ---- (3) current pair ev / nrm / dst (used ~500+ cy later) ----
        const float4* evpA = reinterpret_cast<const float4*>(
            ev + (size_t)gAs * 48 + half * 12);
        const float4 eaA = evpA[0], ebA = evpA[1], ecA = evpA[2];
        const float4* evpB = reinterpret_cast<const float4*>(
            ev + (size_t)gBs * 48 + half * 12);
        const float4 eaB = evpB[0], ebB = evpB[1], ecB = evpB[2];
        const float4 nrA = *reinterpret_cast<const float4*>(nrm + gAs * 16 + half * 4);
        const float4 nrB = *reinterpret_cast<const float4*>(nrm + gBs * 16 + half * 4);
        const int4  dstA = *reinterpret_cast<const int4*>(ei + N_EDGES + gAs * 16 + half * 4);
        const int4  dstB = *reinterpret_cast<const int4*>(ei + N_EDGES + gBs * 16 + half * 4);

        // ---- (4) A fragments (xe in bf16) ----
        bf16x8 afA, afB;
        afA[0] = f2bf(xaA.x); afA[1] = f2bf(xaA.y);
        afA[2] = f2bf(xaA.z); afA[3] = f2bf(xaA.w);
        afA[4] = f2bf(xbA.x); afA[5] = f2bf(xbA.y);
        afA[6] = f2bf(xbA.z); afA[7] = f2bf(xbA.w);
        afB[0] = f2bf(xaB.x); afB[1] = f2bf(xaB.y);
        afB[2] = f2bf(xaB.z); afB[3] = f2bf(xaB.w);
        afB[4] = f2bf(xbB.x); afB[5] = f2bf(xbB.y);
        afB[6] = f2bf(xbB.z); afB[7] = f2bf(xbB.w);

        // ---- (5) acc init via bias tile (c=16, h==1) ----
        f32x4 accA, accB;
        {
            const bf16x8 bfr = *reinterpret_cast<const bf16x8*>(wbase + 16 * 544);
            accA = __builtin_amdgcn_mfma_f32_16x16x32_bf16(
                afA, bfr, (f32x4){0.f, 0.f, 0.f, 0.f}, 0, 0, 0);
            accB = __builtin_amdgcn_mfma_f32_16x16x32_bf16(
                afB, bfr, (f32x4){0.f, 0.f, 0.f, 0.f}, 0, 0, 0);
        }

        // per-edge ev components for this lane's 4 D-rows (edges half*4+q)
        const float evA0[4] = {eaA.x, eaA.w, ebA.z, ecA.y};
        const float evA1[4] = {eaA.y, ebA.x, ebA.w, ecA.z};
        const float evA2[4] = {eaA.z, ebA.y, ecA.x, ecA.w};
        const float evB0[4] = {eaB.x, eaB.w, ebB.z, ecB.y};
        const float evB1[4] = {eaB.y, ebB.x, ebB.w, ecB.z};
        const float evB2[4] = {eaB.z, ebB.y, ecB.x, ecB.w};

        // ---- (6) 16 c-tiles: ONE ds_read feeds TWO independent MFMA+VALU
        // chains. D layout (m89-verified): col=l&15 (=o), row=half*4+q (=edge).
        #pragma unroll
        for (int c = 0; c < 16; ++c) {
            const bf16x8 bfr = *reinterpret_cast<const bf16x8*>(wbase + c * 544);
            const f32x4 tA = __builtin_amdgcn_mfma_f32_16x16x32_bf16(
                afA, bfr, (f32x4){0.f, 0.f, 0.f, 0.f}, 0, 0, 0);
            const f32x4 tB = __builtin_amdgcn_mfma_f32_16x16x32_bf16(
                afB, bfr, (f32x4){0.f, 0.f, 0.f, 0.f}, 0, 0, 0);
            #pragma unroll
            for (int q = 0; q < 4; ++q) {
                float hA = fmaf(evA2[q], w1c2[c],
                           fmaf(evA1[q], w1c1[c],
                           fmaf(evA0[q], w1c0[c], b1s[c])));
                hA = fmaxf(hA, 0.0f);
                accA[q] = fmaf(hA, tA[q], accA[q]);
                float hB = fmaf(evB2[q], w1c2[c],
                           fmaf(evB1[q], w1c1[c],
                           fmaf(evB0[q], w1c0[c], b1s[c])));
                hB = fmaxf(hB, 0.0f);
                accB[q] = fmaf(hB, tB[q], accB[q]);
            }
        }

        // ---- (7) epilogue: tanh, norm scale, f32 scatter-add ----
        #pragma unroll
        for (int q = 0; q < 4; ++q) {
            const float sv = accA[q];
            const float t  = __expf(-2.0f * fabsf(sv));
            const float th = copysignf((1.0f - t) * __builtin_amdgcn_rcpf(1.0f + t), sv);
            const float* nr4 = reinterpret_cast<const float*>(&nrA);
            const int*   ds4 = reinterpret_cast<const int*>(&dstA);
            atomicAdd(out + (size_t)ds4[q] * 16 + r, th * nr4[q]);
        }
        if (vB) {
            #pragma unroll
            for (int q = 0; q < 4; ++q) {
                const float sv = accB[q];
                const float t  = __expf(-2.0f * fabsf(sv));
                const float th = copysignf((1.0f - t) * __builtin_amdgcn_rcpf(1.0f + t), sv);
                const float* nr4 = reinterpret_cast<const float*>(&nrB);
                const int*   ds4 = reinterpret_cast<const int*>(&dstB);
                atomicAdd(out + (size_t)ds4[q] * 16 + r, th * nr4[q]);
            }
        }

        // ---- (8) rotate pipeline state ----
        xaA = xaA1; xbA = xbA1; xaB = xaB1; xbB = xbB1;
        idxA1 = idxA2; idxB1 = idxB2;
        gA += 2 * nw;
        gB += 2 * nw;
    }
    #undef CLAMPG
}

extern "C" void kernel_launch(void* const* d_in, const int* in_sizes, int n_in,
                              void* d_out, int out_size, void* d_ws, size_t ws_size,
                              hipStream_t stream) {
    const float* x   = (const float*)d_in[0];
    const int*   ei  = (const int*)d_in[1];
    const float* ev  = (const float*)d_in[2];
    const float* nrm = (const float*)d_in[3];
    const float* W1  = (const float*)d_in[4];
    const float* b1  = (const float*)d_in[5];
    const float* W2  = (const float*)d_in[6];
    const float* b2  = (const float*)d_in[7];
    float* out = (float*)d_out;

    hipMemsetAsync(out, 0, (size_t)out_size * sizeof(float), stream);

    const int ngroups = N_EDGES / 16;   // 40000, exact
    dim3 grid(2048), block(256);
    hipLaunchKernelGGL(edge_hyper_kernel, grid, block, 0, stream,
                       x, ei, ev, nrm, W1, b1, W2, b2, out, ngroups);
}